// Round 3
// baseline (389.175 us; speedup 1.0000x reference)
//
#include <hip/hip_runtime.h>

// ---------------------------------------------------------------------------
// AdversarialHead, fully fused single-pass kernel.
//
//   h[m,140]    = cf[m,:] @ W1[0:512,:] + W1[512+s0] + W1[512+s1] + W1[512+s2] + b1
//   pred[m,256] = h[m,:] @ W2 + b2
//   L[m,18]     = cf[m,:] @ Wc[0:512,:] + nf[m,:] @ Wc[512:1024,:]  (bias=0)
//   a*(f,a,j)   = softmax over a (32 agents/frame);  m = f*32+a, M = 65536
//
// Weights prepacked in MFMA B-fragment order ([kc][n][lane][8] bf16) so the
// K-loops need no LDS and no barriers: A-frags come straight from global
// (fp32 -> bf16 in-register), B-frags are coalesced 16B/lane L2-resident
// loads. cf is read ONCE (inv's cf-half fused into the gemm1 loop). h lives
// only in LDS; pred is stored directly. 3 barriers per block total.
// ---------------------------------------------------------------------------

using bf16x8  = __attribute__((ext_vector_type(8))) __bf16;
using floatx4 = __attribute__((ext_vector_type(4))) float;

__device__ __forceinline__ unsigned short f2bf(float f) {
    unsigned int u = __float_as_uint(f);
    return (unsigned short)((u + 0x7fffu + ((u >> 16) & 1u)) >> 16);
}
__device__ __forceinline__ bf16x8 cvt8(const float* __restrict__ p) {
    float4 x = *(const float4*)p;
    float4 y = *(const float4*)(p + 4);
    union { bf16x8 v; unsigned short s[8]; } u;
    u.s[0] = f2bf(x.x); u.s[1] = f2bf(x.y); u.s[2] = f2bf(x.z); u.s[3] = f2bf(x.w);
    u.s[4] = f2bf(y.x); u.s[5] = f2bf(y.y); u.s[6] = f2bf(y.z); u.s[7] = f2bf(y.w);
    return u.v;
}

// prepacked ws offsets (bf16 elements)
#define OFF_W1P 0                        // [16][9][64][8]   gemm1 B-frags
#define OFF_W2P (OFF_W1P + 16*9*512)     // [5][16][64][8]   gemm2 B-frags
#define OFF_WCP (OFF_W2P + 5*16*512)     // [32][2][64][8]   inv   B-frags

// d_out element offsets (fp32)
#define OFF_A0 ((size_t)16777216)
#define OFF_A1 ((size_t)17301504)
#define OFF_A2 ((size_t)17694720)

// ---------------------------------------------------------------------------
// Prepack weights fp32 -> bf16 in B-fragment order.
// frag elem: lane l holds B[n*16 + (l&15)][kc*32 + (l>>4)*8 + e], e=0..7.
__global__ __launch_bounds__(256) void prep_kernel(
    const float* __restrict__ W1,   // [530][140]
    const float* __restrict__ W2,   // [140][256]
    const float* __restrict__ Wi0,  // [1024][8]
    const float* __restrict__ Wi1,  // [1024][6]
    const float* __restrict__ Wi2,  // [1024][4]
    unsigned short* __restrict__ ws)
{
    const int T1 = 16*9*512;           // 73728
    const int T2 = T1 + 5*16*512;      // 114688
    const int total = T2 + 32*2*512;   // 147456
    for (int idx = blockIdx.x * 256 + threadIdx.x; idx < total; idx += gridDim.x * 256) {
        unsigned short v = 0;
        if (idx < T1) {                               // W1P: j = B-col of W1[k][j]
            int e = idx & 7, l = (idx >> 3) & 63;
            int n = (idx >> 9) % 9, kc = idx / (9*512);
            int k = kc*32 + ((l >> 4) << 3) + e, j = n*16 + (l & 15);
            if (j < 140) v = f2bf(W1[k*140 + j]);
            ws[OFF_W1P + idx] = v;
        } else if (idx < T2) {                        // W2P (K padded 140->160)
            int i2 = idx - T1;
            int e = i2 & 7, l = (i2 >> 3) & 63;
            int n = (i2 >> 9) & 15, kc = i2 >> 13;
            int k = kc*32 + ((l >> 4) << 3) + e, j = n*16 + (l & 15);
            if (k < 140) v = f2bf(W2[k*256 + j]);
            ws[OFF_W2P + i2] = v;
        } else {                                      // WcP: heads concat (8|6|4)
            int i3 = idx - T2;
            int e = i3 & 7, l = (i3 >> 3) & 63;
            int n = (i3 >> 9) & 1, kc = i3 >> 10;
            int k = kc*32 + ((l >> 4) << 3) + e, j = n*16 + (l & 15);
            if (j < 8)       v = f2bf(Wi0[k*8 + j]);
            else if (j < 14) v = f2bf(Wi1[k*6 + (j - 8)]);
            else if (j < 18) v = f2bf(Wi2[k*4 + (j - 14)]);
            ws[OFF_WCP + i3] = v;
        }
    }
}

// ---------------------------------------------------------------------------
__global__ __launch_bounds__(256) void fused_kernel(
    const float* __restrict__ cf,
    const float* __restrict__ nf,
    const int* __restrict__ actions,   // [2048][3][32]
    const float* __restrict__ W1,      // rows 512..529: one-hot add rows
    const float* __restrict__ b1,
    const float* __restrict__ b2,
    const unsigned short* __restrict__ ws,
    float* __restrict__ outp)
{
    __shared__ alignas(16) __bf16 hs[64 * 168];   // h tile, stride 168 (2-way banks)
    __shared__ float Us[18 * 144];                // one-hot rows of W1 (fp32)
    __shared__ float b1s[144];
    __shared__ float b2s[256];
    __shared__ float Ls[64 * 20];                 // inv logits
    __shared__ float rmx[36], rsc[36];
    __shared__ int   sidx[192];

    const int t = threadIdx.x, w = t >> 6, l = t & 63;
    const int m0 = blockIdx.x * 64;
    const int q = l >> 4, col = l & 15;
    const unsigned short* W1P = ws + OFF_W1P;
    const unsigned short* W2P = ws + OFF_W2P;
    const unsigned short* WCP = ws + OFF_WCP;

    // ---- stage constants (consumed after the K-loops; barrier below covers)
    for (int i = t; i < 18 * 144; i += 256) {
        int s = i / 144, j = i - s * 144;
        Us[i] = (j < 140) ? W1[(512 + s) * 140 + j] : 0.f;
    }
    if (t < 144) b1s[t] = (t < 140) ? b1[t] : 0.f;
    b2s[t] = b2[t];
    if (t < 192) {
        int r = t / 3, tt = t - r * 3;
        int m = m0 + r;
        int start = (tt == 0) ? 0 : (tt == 1 ? 8 : 14);
        sidx[t] = actions[(m >> 5) * 96 + tt * 32 + (m & 31)] + start;
    }

    // A-frag source row for this lane (A layout: row = lane&15, k = quad*8+j)
    const float* cfr = cf + (size_t)(m0 + w * 16 + col) * 512 + q * 8;
    const float* nfr = nf + (size_t)(m0 + w * 16 + col) * 512 + q * 8;

    floatx4 acc1[9], acc3[2];
#pragma unroll
    for (int n = 0; n < 9; ++n) { acc1[n][0]=0.f; acc1[n][1]=0.f; acc1[n][2]=0.f; acc1[n][3]=0.f; }
#pragma unroll
    for (int n = 0; n < 2; ++n) { acc3[n][0]=0.f; acc3[n][1]=0.f; acc3[n][2]=0.f; acc3[n][3]=0.f; }

    // ---- loop A: stream cf once; gemm1 (9 n-tiles) + inv cf-half (2 n-tiles)
    for (int kc = 0; kc < 16; ++kc) {
        bf16x8 av = cvt8(cfr + kc * 32);
        const unsigned short* bp = W1P + (size_t)(kc * 9) * 512 + l * 8;
#pragma unroll
        for (int n = 0; n < 9; ++n)
            acc1[n] = __builtin_amdgcn_mfma_f32_16x16x32_bf16(
                av, *(const bf16x8*)(bp + n * 512), acc1[n], 0, 0, 0);
        const unsigned short* cp = WCP + (size_t)(kc * 2) * 512 + l * 8;
        acc3[0] = __builtin_amdgcn_mfma_f32_16x16x32_bf16(
            av, *(const bf16x8*)(cp), acc3[0], 0, 0, 0);
        acc3[1] = __builtin_amdgcn_mfma_f32_16x16x32_bf16(
            av, *(const bf16x8*)(cp + 512), acc3[1], 0, 0, 0);
    }

    // ---- loop B: stream nf; inv nf-half
    for (int kc = 0; kc < 16; ++kc) {
        bf16x8 av = cvt8(nfr + kc * 32);
        const unsigned short* cp = WCP + (size_t)((16 + kc) * 2) * 512 + l * 8;
        acc3[0] = __builtin_amdgcn_mfma_f32_16x16x32_bf16(
            av, *(const bf16x8*)(cp), acc3[0], 0, 0, 0);
        acc3[1] = __builtin_amdgcn_mfma_f32_16x16x32_bf16(
            av, *(const bf16x8*)(cp + 512), acc3[1], 0, 0, 0);
    }

    __syncthreads();   // Us/b1s/sidx staged -> readable

    // ---- epilogue 1: h = acc1 + b1 + one-hot rows; write bf16 to LDS
    // C/D layout: col = lane&15, row = quad*4 + i
    const int r0 = w * 16 + (q << 2);
#pragma unroll
    for (int i = 0; i < 4; ++i) {
        int rr = r0 + i;
        int s0 = sidx[rr * 3], s1 = sidx[rr * 3 + 1], s2 = sidx[rr * 3 + 2];
#pragma unroll
        for (int n = 0; n < 9; ++n) {
            int j = n * 16 + col;
            float v = acc1[n][i] + b1s[j] + Us[s0 * 144 + j] + Us[s1 * 144 + j] + Us[s2 * 144 + j];
            ((unsigned short*)hs)[rr * 168 + j] = f2bf(v);
        }
    }
    {   // zero pad cols 144..159 (phase-2 K reads zeros there)
        int rr = t >> 2, g = t & 3;
        ushort4 z; z.x = z.y = z.z = z.w = 0;
        *(ushort4*)((unsigned short*)hs + rr * 168 + 144 + g * 4) = z;
    }
    __syncthreads();

    // ---- phase 2: pred = h @ W2 + b2 (K=160, 5 chunks), store fp32
    floatx4 acc2[16];
#pragma unroll
    for (int n = 0; n < 16; ++n) { acc2[n][0]=0.f; acc2[n][1]=0.f; acc2[n][2]=0.f; acc2[n][3]=0.f; }

    for (int kc = 0; kc < 5; ++kc) {
        bf16x8 av = *(const bf16x8*)&hs[(w * 16 + col) * 168 + kc * 32 + q * 8];
        const unsigned short* bp = W2P + (size_t)(kc * 16) * 512 + l * 8;
#pragma unroll
        for (int n = 0; n < 16; ++n)
            acc2[n] = __builtin_amdgcn_mfma_f32_16x16x32_bf16(
                av, *(const bf16x8*)(bp + n * 512), acc2[n], 0, 0, 0);
    }
#pragma unroll
    for (int n = 0; n < 16; ++n) {
        int j = n * 16 + col;
        float bj = b2s[j];
#pragma unroll
        for (int i = 0; i < 4; ++i)
            outp[(size_t)(m0 + r0 + i) * 256 + j] = acc2[n][i] + bj;
    }

    // ---- phase 3: inv logits -> LDS -> softmax over 32 agents per frame
#pragma unroll
    for (int n = 0; n < 2; ++n) {
        int j = n * 16 + col;
        if (j < 18) {
#pragma unroll
            for (int i = 0; i < 4; ++i) Ls[(r0 + i) * 20 + j] = acc3[n][i];
        }
    }
    __syncthreads();

    if (t < 36) {
        int fr = t / 18, j = t - fr * 18;
        float mx = -1e30f;
        for (int a = 0; a < 32; ++a) mx = fmaxf(mx, Ls[(fr * 32 + a) * 20 + j]);
        float s = 0.f;
        for (int a = 0; a < 32; ++a) s += expf(Ls[(fr * 32 + a) * 20 + j] - mx);
        rmx[t] = mx; rsc[t] = 1.f / s;
    }
    __syncthreads();

#pragma unroll
    for (int it = 0; it < 5; ++it) {               // 64*18 = 1152 outputs
        int idx = t + it * 256;
        if (idx < 1152) {
            int r = idx / 18, j = idx - r * 18;
            int fr = r >> 5;
            float v = expf(Ls[r * 20 + j] - rmx[fr * 18 + j]) * rsc[fr * 18 + j];
            int m = m0 + r;
            size_t o;
            if (j < 8)       o = OFF_A0 + (size_t)m * 8 + j;
            else if (j < 14) o = OFF_A1 + (size_t)m * 6 + (j - 8);
            else             o = OFF_A2 + (size_t)m * 4 + (j - 14);
            outp[o] = v;
        }
    }
}

// ---------------------------------------------------------------------------
extern "C" void kernel_launch(void* const* d_in, const int* in_sizes, int n_in,
                              void* d_out, int out_size, void* d_ws, size_t ws_size,
                              hipStream_t stream)
{
    const float* cf  = (const float*)d_in[0];
    const float* nf  = (const float*)d_in[1];
    const int*   act = (const int*)d_in[2];
    const float* W1  = (const float*)d_in[3];
    const float* b1  = (const float*)d_in[4];
    const float* W2  = (const float*)d_in[5];
    const float* b2  = (const float*)d_in[6];
    const float* Wi0 = (const float*)d_in[7];
    const float* Wi1 = (const float*)d_in[9];
    const float* Wi2 = (const float*)d_in[11];

    unsigned short* ws = (unsigned short*)d_ws;
    float* outp = (float*)d_out;

    hipLaunchKernelGGL(prep_kernel, dim3(144), dim3(256), 0, stream,
                       W1, W2, Wi0, Wi1, Wi2, ws);
    hipLaunchKernelGGL(fused_kernel, dim3(1024), dim3(256), 0, stream,
                       cf, nf, act, W1, b1, b2, ws, outp);
}

// Round 4
// 364.467 us; speedup vs baseline: 1.0678x; 1.0678x over previous
//
#include <hip/hip_runtime.h>

// ---------------------------------------------------------------------------
// AdversarialHead, fully fused single-pass kernel.
//
//   h[m,140]    = cf[m,:] @ W1[0:512,:] + W1[512+s0] + W1[512+s1] + W1[512+s2] + b1
//   pred[m,256] = h[m,:] @ W2 + b2
//   L[m,18]     = cf[m,:] @ Wc[0:512,:] + nf[m,:] @ Wc[512:1024,:]  (bias=0)
//   a*(f,a,j)   = softmax over a (32 agents/frame);  m = f*32+a, M = 65536
//
// Round-4 changes vs round-3 (which hit a 1.15 TB/s wall = 12.5% of HBM peak):
//  * K-phase rotation: block b traverses kc = (b + i) & 15. Rows are 2048 B
//    apart, so channel = (row*8 + colchunk) mod NCH; with all blocks at the
//    same kc phase only ~1/8 of channels were active. Rotation covers all
//    (row-residue x col-phase) combinations -> full channel parallelism.
//  * 1-deep A-prefetch (cross-iteration load/use decoupling).
//  * Us staging loads hoisted into registers (no serialized HBM round-trips).
// ---------------------------------------------------------------------------

using bf16x8  = __attribute__((ext_vector_type(8))) __bf16;
using floatx4 = __attribute__((ext_vector_type(4))) float;

__device__ __forceinline__ unsigned short f2bf(float f) {
    unsigned int u = __float_as_uint(f);
    return (unsigned short)((u + 0x7fffu + ((u >> 16) & 1u)) >> 16);
}
__device__ __forceinline__ bf16x8 cvt8r(float4 x, float4 y) {
    union { bf16x8 v; unsigned short s[8]; } u;
    u.s[0] = f2bf(x.x); u.s[1] = f2bf(x.y); u.s[2] = f2bf(x.z); u.s[3] = f2bf(x.w);
    u.s[4] = f2bf(y.x); u.s[5] = f2bf(y.y); u.s[6] = f2bf(y.z); u.s[7] = f2bf(y.w);
    return u.v;
}

// prepacked ws offsets (bf16 elements)
#define OFF_W1P 0                        // [16][9][64][8]   gemm1 B-frags
#define OFF_W2P (OFF_W1P + 16*9*512)     // [5][16][64][8]   gemm2 B-frags
#define OFF_WCP (OFF_W2P + 5*16*512)     // [32][2][64][8]   inv   B-frags

// d_out element offsets (fp32)
#define OFF_A0 ((size_t)16777216)
#define OFF_A1 ((size_t)17301504)
#define OFF_A2 ((size_t)17694720)

// ---------------------------------------------------------------------------
// Prepack weights fp32 -> bf16 in B-fragment order.
// frag elem: lane l holds B[n*16 + (l&15)][kc*32 + (l>>4)*8 + e], e=0..7.
__global__ __launch_bounds__(256) void prep_kernel(
    const float* __restrict__ W1,   // [530][140]
    const float* __restrict__ W2,   // [140][256]
    const float* __restrict__ Wi0,  // [1024][8]
    const float* __restrict__ Wi1,  // [1024][6]
    const float* __restrict__ Wi2,  // [1024][4]
    unsigned short* __restrict__ ws)
{
    const int T1 = 16*9*512;           // 73728
    const int T2 = T1 + 5*16*512;      // 114688
    const int total = T2 + 32*2*512;   // 147456
    for (int idx = blockIdx.x * 256 + threadIdx.x; idx < total; idx += gridDim.x * 256) {
        unsigned short v = 0;
        if (idx < T1) {                               // W1P
            int e = idx & 7, l = (idx >> 3) & 63;
            int n = (idx >> 9) % 9, kc = idx / (9*512);
            int k = kc*32 + ((l >> 4) << 3) + e, j = n*16 + (l & 15);
            if (j < 140) v = f2bf(W1[k*140 + j]);
            ws[OFF_W1P + idx] = v;
        } else if (idx < T2) {                        // W2P (K padded 140->160)
            int i2 = idx - T1;
            int e = i2 & 7, l = (i2 >> 3) & 63;
            int n = (i2 >> 9) & 15, kc = i2 >> 13;
            int k = kc*32 + ((l >> 4) << 3) + e, j = n*16 + (l & 15);
            if (k < 140) v = f2bf(W2[k*256 + j]);
            ws[OFF_W2P + i2] = v;
        } else {                                      // WcP: heads concat (8|6|4)
            int i3 = idx - T2;
            int e = i3 & 7, l = (i3 >> 3) & 63;
            int n = (i3 >> 9) & 1, kc = i3 >> 10;
            int k = kc*32 + ((l >> 4) << 3) + e, j = n*16 + (l & 15);
            if (j < 8)       v = f2bf(Wi0[k*8 + j]);
            else if (j < 14) v = f2bf(Wi1[k*6 + (j - 8)]);
            else if (j < 18) v = f2bf(Wi2[k*4 + (j - 14)]);
            ws[OFF_WCP + i3] = v;
        }
    }
}

// ---------------------------------------------------------------------------
__global__ __launch_bounds__(256) void fused_kernel(
    const float* __restrict__ cf,
    const float* __restrict__ nf,
    const int* __restrict__ actions,   // [2048][3][32]
    const float* __restrict__ W1,      // rows 512..529: one-hot add rows
    const float* __restrict__ b1,
    const float* __restrict__ b2,
    const unsigned short* __restrict__ ws,
    float* __restrict__ outp)
{
    __shared__ alignas(16) __bf16 hs[64 * 168];   // h tile, stride 168 (2-way banks)
    __shared__ float Us[18 * 144];                // one-hot rows of W1 (fp32)
    __shared__ float b1s[144];
    __shared__ float b2s[256];
    __shared__ float Ls[64 * 20];                 // inv logits
    __shared__ float rmx[36], rsc[36];
    __shared__ int   sidx[192];

    const int t = threadIdx.x, w = t >> 6, l = t & 63;
    const int m0 = blockIdx.x * 64;
    const int q = l >> 4, col = l & 15;
    const unsigned short* W1P = ws + OFF_W1P;
    const unsigned short* W2P = ws + OFF_W2P;
    const unsigned short* WCP = ws + OFF_WCP;

    // ---- stage constants: hoist loads into regs (all in flight), then LDS
    {
        float uv[11];
#pragma unroll
        for (int it = 0; it < 11; ++it) {
            int i = t + it * 256;
            uv[it] = 0.f;
            if (i < 18 * 144) {
                int s = i / 144, j = i - s * 144;
                if (j < 140) uv[it] = W1[(512 + s) * 140 + j];
            }
        }
        float bv1 = (t < 140) ? b1[t] : 0.f;
        float bv2 = b2[t];
        int sv = 0;
        if (t < 192) {
            int r = t / 3, tt = t - r * 3;
            int m = m0 + r;
            int start = (tt == 0) ? 0 : (tt == 1 ? 8 : 14);
            sv = actions[(m >> 5) * 96 + tt * 32 + (m & 31)] + start;
        }
#pragma unroll
        for (int it = 0; it < 11; ++it) {
            int i = t + it * 256;
            if (i < 18 * 144) Us[i] = uv[it];
        }
        if (t < 144) b1s[t] = bv1;
        b2s[t] = bv2;
        if (t < 192) sidx[t] = sv;
    }

    // A-frag source row for this lane (A layout: row = lane&15, k = quad*8+j)
    const float* cfr = cf + (size_t)(m0 + w * 16 + col) * 512 + q * 8;
    const float* nfr = nf + (size_t)(m0 + w * 16 + col) * 512 + q * 8;

    floatx4 acc1[9], acc3[2];
#pragma unroll
    for (int n = 0; n < 9; ++n) { acc1[n][0]=0.f; acc1[n][1]=0.f; acc1[n][2]=0.f; acc1[n][3]=0.f; }
#pragma unroll
    for (int n = 0; n < 2; ++n) { acc3[n][0]=0.f; acc3[n][1]=0.f; acc3[n][2]=0.f; acc3[n][3]=0.f; }

    const int base = blockIdx.x & 15;   // K-phase rotation (channel spread)

    // ---- loop A: stream cf once; gemm1 (9 n-tiles) + inv cf-half (2 n-tiles)
    {
        float4 c0 = *(const float4*)(cfr + base * 32);
        float4 c1 = *(const float4*)(cfr + base * 32 + 4);
        for (int i = 0; i < 16; ++i) {
            const int kc  = (base + i) & 15;
            const int kn  = (base + i + 1) & 15;
            float4 n0 = *(const float4*)(cfr + kn * 32);       // prefetch next
            float4 n1 = *(const float4*)(cfr + kn * 32 + 4);
            bf16x8 av = cvt8r(c0, c1);
            const unsigned short* bp = W1P + (size_t)(kc * 9) * 512 + l * 8;
#pragma unroll
            for (int n = 0; n < 9; ++n)
                acc1[n] = __builtin_amdgcn_mfma_f32_16x16x32_bf16(
                    av, *(const bf16x8*)(bp + n * 512), acc1[n], 0, 0, 0);
            const unsigned short* cp = WCP + (size_t)(kc * 2) * 512 + l * 8;
            acc3[0] = __builtin_amdgcn_mfma_f32_16x16x32_bf16(
                av, *(const bf16x8*)(cp), acc3[0], 0, 0, 0);
            acc3[1] = __builtin_amdgcn_mfma_f32_16x16x32_bf16(
                av, *(const bf16x8*)(cp + 512), acc3[1], 0, 0, 0);
            c0 = n0; c1 = n1;
        }
    }

    // ---- loop B: stream nf; inv nf-half
    {
        float4 c0 = *(const float4*)(nfr + base * 32);
        float4 c1 = *(const float4*)(nfr + base * 32 + 4);
        for (int i = 0; i < 16; ++i) {
            const int kc  = (base + i) & 15;
            const int kn  = (base + i + 1) & 15;
            float4 n0 = *(const float4*)(nfr + kn * 32);
            float4 n1 = *(const float4*)(nfr + kn * 32 + 4);
            bf16x8 av = cvt8r(c0, c1);
            const unsigned short* cp = WCP + (size_t)((16 + kc) * 2) * 512 + l * 8;
            acc3[0] = __builtin_amdgcn_mfma_f32_16x16x32_bf16(
                av, *(const bf16x8*)(cp), acc3[0], 0, 0, 0);
            acc3[1] = __builtin_amdgcn_mfma_f32_16x16x32_bf16(
                av, *(const bf16x8*)(cp + 512), acc3[1], 0, 0, 0);
            c0 = n0; c1 = n1;
        }
    }

    __syncthreads();   // Us/b1s/sidx staged -> readable

    // ---- epilogue 1: h = acc1 + b1 + one-hot rows; write bf16 to LDS
    // C/D layout: col = lane&15, row = quad*4 + i
    const int r0 = w * 16 + (q << 2);
#pragma unroll
    for (int i = 0; i < 4; ++i) {
        int rr = r0 + i;
        int s0 = sidx[rr * 3], s1 = sidx[rr * 3 + 1], s2 = sidx[rr * 3 + 2];
#pragma unroll
        for (int n = 0; n < 9; ++n) {
            int j = n * 16 + col;
            float v = acc1[n][i] + b1s[j] + Us[s0 * 144 + j] + Us[s1 * 144 + j] + Us[s2 * 144 + j];
            ((unsigned short*)hs)[rr * 168 + j] = f2bf(v);
        }
    }
    {   // zero pad cols 144..159 (phase-2 K reads zeros there)
        int rr = t >> 2, g = t & 3;
        ushort4 z; z.x = z.y = z.z = z.w = 0;
        *(ushort4*)((unsigned short*)hs + rr * 168 + 144 + g * 4) = z;
    }
    // inv logits -> LDS (frees acc3 before phase 2)
#pragma unroll
    for (int n = 0; n < 2; ++n) {
        int j = n * 16 + col;
        if (j < 18) {
#pragma unroll
            for (int i = 0; i < 4; ++i) Ls[(r0 + i) * 20 + j] = acc3[n][i];
        }
    }
    __syncthreads();

    // ---- phase 2: pred = h @ W2 + b2 (K=160, 5 chunks), store fp32
    floatx4 acc2[16];
#pragma unroll
    for (int n = 0; n < 16; ++n) { acc2[n][0]=0.f; acc2[n][1]=0.f; acc2[n][2]=0.f; acc2[n][3]=0.f; }

    for (int kc = 0; kc < 5; ++kc) {
        bf16x8 av = *(const bf16x8*)&hs[(w * 16 + col) * 168 + kc * 32 + q * 8];
        const unsigned short* bp = W2P + (size_t)(kc * 16) * 512 + l * 8;
#pragma unroll
        for (int n = 0; n < 16; ++n)
            acc2[n] = __builtin_amdgcn_mfma_f32_16x16x32_bf16(
                av, *(const bf16x8*)(bp + n * 512), acc2[n], 0, 0, 0);
    }
#pragma unroll
    for (int n = 0; n < 16; ++n) {
        int j = n * 16 + col;
        float bj = b2s[j];
#pragma unroll
        for (int i = 0; i < 4; ++i)
            outp[(size_t)(m0 + r0 + i) * 256 + j] = acc2[n][i] + bj;
    }

    // ---- phase 3: softmax over 32 agents per frame
    if (t < 36) {
        int fr = t / 18, j = t - fr * 18;
        float mx = -1e30f;
        for (int a = 0; a < 32; ++a) mx = fmaxf(mx, Ls[(fr * 32 + a) * 20 + j]);
        float s = 0.f;
        for (int a = 0; a < 32; ++a) s += expf(Ls[(fr * 32 + a) * 20 + j] - mx);
        rmx[t] = mx; rsc[t] = 1.f / s;
    }
    __syncthreads();

#pragma unroll
    for (int it = 0; it < 5; ++it) {               // 64*18 = 1152 outputs
        int idx = t + it * 256;
        if (idx < 1152) {
            int r = idx / 18, j = idx - r * 18;
            int fr = r >> 5;
            float v = expf(Ls[r * 20 + j] - rmx[fr * 18 + j]) * rsc[fr * 18 + j];
            int m = m0 + r;
            size_t o;
            if (j < 8)       o = OFF_A0 + (size_t)m * 8 + j;
            else if (j < 14) o = OFF_A1 + (size_t)m * 6 + (j - 8);
            else             o = OFF_A2 + (size_t)m * 4 + (j - 14);
            outp[o] = v;
        }
    }
}

// ---------------------------------------------------------------------------
extern "C" void kernel_launch(void* const* d_in, const int* in_sizes, int n_in,
                              void* d_out, int out_size, void* d_ws, size_t ws_size,
                              hipStream_t stream)
{
    const float* cf  = (const float*)d_in[0];
    const float* nf  = (const float*)d_in[1];
    const int*   act = (const int*)d_in[2];
    const float* W1  = (const float*)d_in[3];
    const float* b1  = (const float*)d_in[4];
    const float* W2  = (const float*)d_in[5];
    const float* b2  = (const float*)d_in[6];
    const float* Wi0 = (const float*)d_in[7];
    const float* Wi1 = (const float*)d_in[9];
    const float* Wi2 = (const float*)d_in[11];

    unsigned short* ws = (unsigned short*)d_ws;
    float* outp = (float*)d_out;

    hipLaunchKernelGGL(prep_kernel, dim3(144), dim3(256), 0, stream,
                       W1, W2, Wi0, Wi1, Wi2, ws);
    hipLaunchKernelGGL(fused_kernel, dim3(1024), dim3(256), 0, stream,
                       cf, nf, act, W1, b1, b2, ws, outp);
}